// Round 1
// 314.453 us; speedup vs baseline: 1.0197x; 1.0197x over previous
//
#include <hip/hip_runtime.h>
#include <stdint.h>

// out[b,o,h,w] = sum_c x[b,c,h,w] * Wg[(h%4)*4+(w%4), o, c]
// B=16, Cs=Ct=512, H=W=64.
// Round-3: bigger tiles to halve CU ingress per FLOP.
//   Block = 512 threads (8 waves = 2 m-halves x 4 q), tile M=128, Nq=128
//   (8 pixel rows), BK=32, 16 K-steps, 32 MFMA/wave/step.
//   Grid (nb=32, mb=4, r=4): x re-read 8->4x, A re-read 64->32x.
//   As reads XOR-swizzled (chunk ^= row&3) via pre-swizzled glds source
//   (LDS dest linear, rule #21) + swizzled ds_read -> conflict-free b128.

typedef __attribute__((ext_vector_type(8))) short short8;
typedef __attribute__((ext_vector_type(4))) float f32x4;

#define CS 512
#define CT 512
#define HW 4096
#define BK 32
#define MT 128      // out-channel rows per block
#define NR 8        // pixel rows per block
#define BPITCH 40   // Bs row pitch in uint16 (80B, 16B-multiple)

__device__ __forceinline__ uint16_t f32_to_bf16(float f) {
    uint32_t u = __builtin_bit_cast(uint32_t, f);
    u += 0x7FFFu + ((u >> 16) & 1u);     // RNE
    return (uint16_t)(u >> 16);
}

__global__ __launch_bounds__(256)
void w2_cvt(const float* __restrict__ Wg, uint16_t* __restrict__ W2) {
    int idx = (blockIdx.x * 256 + threadIdx.x) * 8;
    float4 a = *(const float4*)(Wg + idx);
    float4 b = *(const float4*)(Wg + idx + 4);
    uint16_t o[8];
    o[0]=f32_to_bf16(a.x); o[1]=f32_to_bf16(a.y); o[2]=f32_to_bf16(a.z); o[3]=f32_to_bf16(a.w);
    o[4]=f32_to_bf16(b.x); o[5]=f32_to_bf16(b.y); o[6]=f32_to_bf16(b.z); o[7]=f32_to_bf16(b.w);
    *(short8*)(W2 + idx) = *(short8*)o;
}

template<bool USE_W2>
__global__ __launch_bounds__(512, 2)
void gwl_main(const float* __restrict__ x, const float* __restrict__ Wg,
              const uint16_t* __restrict__ W2, float* __restrict__ out) {
    const int nb = blockIdx.x;   // pixel-row block: rows 8*nb..8*nb+7 of (b*16+h4)
    const int mb = blockIdx.y;   // out-channel block (128 rows)
    const int r  = blockIdx.z;   // h%4 phase
    const int m0 = mb * MT;

    // LDS: As [4 q][128 m][32 k] bf16, glds-linear, k-chunk XOR swizzled: 32KB
    //      Bs [4 q][128 n][BPITCH] bf16: 40KB
    //      T  (epilogue, aliased over As/Bs) [16 m][8 rho][68 w] f32: 34816B
    __shared__ __align__(16) unsigned char smem[73728];
    uint16_t* As = (uint16_t*)smem;
    uint16_t* Bs = (uint16_t*)(smem + 32768);
    float*    T  = (float*)smem;

    const int tid  = threadIdx.x;
    const int lane = tid & 63;
    const int wave = tid >> 6;      // 0..7
    const int q    = wave & 3;      // w%4 phase this wave computes
    const int mw   = wave >> 2;     // m-half (64 rows)
    const int lr = lane & 15, qd = lane >> 4;

    // ---- B staging coords: thread = (w16 = tid&15, rho = (tid>>4)&7, kw = tid>>7)
    const int w16 = tid & 15;
    const int rho = (tid >> 4) & 7;
    const int kw  = tid >> 7;           // 0..3, 8 k's each
    const int rg  = nb * NR + rho;      // global (b*16 + h4) row
    const int bb  = rg >> 4;
    const int h4  = rg & 15;
    const float* bbase = x + (size_t)bb * CS * HW
                           + (size_t)((h4 * 4 + r) * 64 + w16 * 4);

    // ---- A staging (bf16 via global_load_lds): wave (q, mw) loads its 64x32 tile
    const uint16_t* abase = USE_W2
        ? W2 + ((size_t)(r * 4 + q) * CT + m0 + mw * 64) * CS : (const uint16_t*)nullptr;

    float4 breg[8];
    auto loadB = [&](int k0) {
        const float* p = bbase + (size_t)(k0 + kw * 8) * HW;
        #pragma unroll
        for (int cc = 0; cc < 8; ++cc) breg[cc] = *(const float4*)(p + (size_t)cc * HW);
    };
    auto writeB = [&]() {
        #pragma unroll
        for (int qq = 0; qq < 4; ++qq) {
            uint16_t tmp[8];
            #pragma unroll
            for (int cc = 0; cc < 8; ++cc)
                tmp[cc] = f32_to_bf16(((const float*)&breg[cc])[qq]);
            *(short8*)(Bs + (qq * 128 + rho * 16 + w16) * BPITCH + kw * 8) = *(short8*)tmp;
        }
    };
    auto stageA_glds = [&](int k0) {
        #pragma unroll
        for (int t = 0; t < 4; ++t) {
            // dest (row=t*16+(lane>>2), chunk=lane&3) receives global chunk
            // (lane&3)^(row&3): pre-swizzled source, linear LDS dest.
            const uint16_t* src = abase + (size_t)(t * 16 + (lane >> 2)) * CS
                                        + k0 + (((lane & 3) ^ ((lane >> 2) & 3)) * 8);
            uint16_t* dst = As + (q * 128 + mw * 64) * 32 + t * 512;  // + lane*8 by HW
            __builtin_amdgcn_global_load_lds(
                (const __attribute__((address_space(1))) void*)src,
                (__attribute__((address_space(3))) void*)dst, 16, 0, 0);
        }
    };
    auto stageA_fp32 = [&](int k0) {
        const int qa = tid >> 7, rem = tid & 127;
        const int ka = rem & 7, ma = rem >> 3;
        const float* ap = Wg + ((size_t)(r * 4 + qa) * CT + m0 + ma) * CS + k0 + ka * 4;
        const int kc = (((ka >> 1) ^ (ma & 3)) * 8) + (ka & 1) * 4;  // swizzled elem off
        #pragma unroll
        for (int it = 0; it < 8; ++it) {
            float4 v = *(const float4*)(ap + (size_t)it * 16 * CS);
            uint16_t tmp[4] = {f32_to_bf16(v.x), f32_to_bf16(v.y),
                               f32_to_bf16(v.z), f32_to_bf16(v.w)};
            *(uint64_t*)(As + (qa * 128 + ma + it * 16) * 32 + kc) =
                *(const uint64_t*)tmp;
        }
    };

    f32x4 acc[4][8] = {};

    // prologue: fill tile 0, prefetch B regs for tile 1
    loadB(0);
    if (USE_W2) stageA_glds(0); else stageA_fp32(0);
    writeB();
    loadB(BK);

    const uint16_t* Asq = As + (q * 128 + mw * 64) * 32;
    const uint16_t* Bsq = Bs + q * 128 * BPITCH;

    for (int k = 0; k < 16; ++k) {
        __syncthreads();                       // tile k fill complete
        short8 afr[4], bfr[8];
        #pragma unroll
        for (int i = 0; i < 4; ++i)
            afr[i] = *(const short8*)(Asq + (i * 16 + lr) * 32 + ((qd ^ (lr & 3)) * 8));
        #pragma unroll
        for (int j = 0; j < 8; ++j)
            bfr[j] = *(const short8*)(Bsq + (j * 16 + lr) * BPITCH + qd * 8);
        if (k < 15) {
            __syncthreads();                   // all frag reads landed; LDS free
            if (USE_W2) stageA_glds((k + 1) * BK); else stageA_fp32((k + 1) * BK);
            writeB();                          // tile k+1 from breg
            if (k < 14) loadB((k + 2) * BK);
        }
        #pragma unroll
        for (int i = 0; i < 4; ++i)
            #pragma unroll
            for (int j = 0; j < 8; ++j)
                acc[i][j] = __builtin_amdgcn_mfma_f32_16x16x32_bf16(
                    afr[i], bfr[j], acc[i][j], 0, 0, 0);
    }

    // ---- epilogue: LDS transpose -> full-line float4 stores
    // acc[i][j][g]: m = m0 + mw*64 + i*16 + qd*4+g, pixel n = j*16+lr
    //   -> rho = j, w16 = lr, w = lr*4 + q.
    // chunk ic = mw*4 + i covers 16 consecutive out-channels.
    const int m16s = tid >> 5;        // 0..15
    const int rs   = (tid >> 2) & 7;  // 0..7
    const int ws   = (tid & 3) * 16;
    const int rgs  = nb * NR + rs;
    const int obb  = rgs >> 4;
    const int oh4  = rgs & 15;
    #pragma unroll
    for (int ic = 0; ic < 8; ++ic) {
        __syncthreads();                       // prior reads of smem done
        if (mw == (ic >> 2)) {
            const int i = ic & 3;
            #pragma unroll
            for (int j = 0; j < 8; ++j)
                #pragma unroll
                for (int g = 0; g < 4; ++g)
                    T[((qd * 4 + g) * 8 + j) * 68 + lr * 4 + q] = acc[i][j][g];
        }
        __syncthreads();
        float* op = out + ((size_t)obb * CT + m0 + ic * 16 + m16s) * HW
                        + (oh4 * 4 + r) * 64 + ws;
        const float* tp = T + (m16s * 8 + rs) * 68 + ws;
        #pragma unroll
        for (int c = 0; c < 4; ++c)
            ((float4*)op)[c] = ((const float4*)tp)[c];
    }
}

extern "C" void kernel_launch(void* const* d_in, const int* in_sizes, int n_in,
                              void* d_out, int out_size, void* d_ws, size_t ws_size,
                              hipStream_t stream) {
    const float* x  = (const float*)d_in[0];
    const float* Wg = (const float*)d_in[1];
    float* out = (float*)d_out;
    dim3 grid(32, 4, 4);   // nb fastest: mb siblings (id stride 32) share an XCD
    if (ws_size >= (size_t)16 * 512 * 512 * 2) {
        uint16_t* W2 = (uint16_t*)d_ws;
        w2_cvt<<<2048, 256, 0, stream>>>(Wg, W2);
        gwl_main<true><<<grid, 512, 0, stream>>>(x, Wg, W2, out);
    } else {
        gwl_main<false><<<grid, 512, 0, stream>>>(x, Wg, nullptr, out);
    }
}

// Round 2
// 298.409 us; speedup vs baseline: 1.0745x; 1.0538x over previous
//
#include <hip/hip_runtime.h>
#include <stdint.h>

// out[b,o,h,w] = sum_c x[b,c,h,w] * Wg[(h%4)*4+(w%4), o, c]
// B=16, Cs=Ct=512, H=W=64.
// Round-4: T3/T4 port — double-buffered LDS, ONE raw barrier per K-step,
//   counted s_waitcnt vmcnt(8) (loadB x-prefetch stays in flight across the
//   barrier; only the 4 glds must land). Fixed As swizzle: stored chunk =
//   global chunk ^ ((row>>1)&3)  (64B rows -> slot bijection per 8 lanes).
//   Block = 512 threads (8 waves = 2 m-halves x 4 q), tile M=128, Nq=128,
//   BK=32, 16 K-steps, 32 MFMA/wave/step. Grid (nb=32, mb=4, r=4).

typedef __attribute__((ext_vector_type(8))) short short8;
typedef __attribute__((ext_vector_type(4))) float f32x4;

#define CS 512
#define CT 512
#define HW 4096
#define BK 32
#define MT 128      // out-channel rows per block
#define NR 8        // pixel rows per block
#define BPITCH 40   // Bs row pitch in uint16 (80B, 16B-multiple, conflict-free)
#define BUFB 73728  // bytes per LDS buffer: As 32KB + Bs 40KB

__device__ __forceinline__ uint16_t f32_to_bf16(float f) {
    uint32_t u = __builtin_bit_cast(uint32_t, f);
    u += 0x7FFFu + ((u >> 16) & 1u);     // RNE
    return (uint16_t)(u >> 16);
}

__global__ __launch_bounds__(256)
void w2_cvt(const float* __restrict__ Wg, uint16_t* __restrict__ W2) {
    int idx = (blockIdx.x * 256 + threadIdx.x) * 8;
    float4 a = *(const float4*)(Wg + idx);
    float4 b = *(const float4*)(Wg + idx + 4);
    uint16_t o[8];
    o[0]=f32_to_bf16(a.x); o[1]=f32_to_bf16(a.y); o[2]=f32_to_bf16(a.z); o[3]=f32_to_bf16(a.w);
    o[4]=f32_to_bf16(b.x); o[5]=f32_to_bf16(b.y); o[6]=f32_to_bf16(b.z); o[7]=f32_to_bf16(b.w);
    *(short8*)(W2 + idx) = *(short8*)o;
}

template<bool USE_W2>
__global__ __launch_bounds__(512, 2)
void gwl_main(const float* __restrict__ x, const float* __restrict__ Wg,
              const uint16_t* __restrict__ W2, float* __restrict__ out) {
    const int nb = blockIdx.x;   // pixel-row block: rows 8*nb..8*nb+7 of (b*16+h4)
    const int mb = blockIdx.y;   // out-channel block (128 rows)
    const int r  = blockIdx.z;   // h%4 phase
    const int m0 = mb * MT;

    // LDS: 2 buffers x (As [4q][128m][32k] bf16 32KB + Bs [4q][128n][BPITCH] 40KB)
    //      T (epilogue, aliased over buffer 0) [16 m][8 rho][68 w] f32: 34816B
    __shared__ __align__(16) unsigned char smem[2 * BUFB];
    float* T = (float*)smem;

    const int tid  = threadIdx.x;
    const int lane = tid & 63;
    const int wave = tid >> 6;      // 0..7
    const int q    = wave & 3;      // w%4 phase this wave computes
    const int mw   = wave >> 2;     // m-half (64 rows)
    const int lr = lane & 15, qd = lane >> 4;

    // ---- B staging coords: thread = (w16 = tid&15, rho = (tid>>4)&7, kw = tid>>7)
    const int w16 = tid & 15;
    const int rho = (tid >> 4) & 7;
    const int kw  = tid >> 7;           // 0..3, 8 k's each
    const int rg  = nb * NR + rho;      // global (b*16 + h4) row
    const int bb  = rg >> 4;
    const int h4  = rg & 15;
    const float* bbase = x + (size_t)bb * CS * HW
                           + (size_t)((h4 * 4 + r) * 64 + w16 * 4);

    // ---- A staging (bf16 via global_load_lds): wave (q, mw) loads its 64x32 tile
    const uint16_t* abase = USE_W2
        ? W2 + ((size_t)(r * 4 + q) * CT + m0 + mw * 64) * CS : (const uint16_t*)nullptr;

    float4 breg[8];
    auto loadB = [&](int k0) {
        const float* p = bbase + (size_t)(k0 + kw * 8) * HW;
        #pragma unroll
        for (int cc = 0; cc < 8; ++cc) breg[cc] = *(const float4*)(p + (size_t)cc * HW);
    };
    auto writeB = [&](uint16_t* BsD) {
        #pragma unroll
        for (int qq = 0; qq < 4; ++qq) {
            uint16_t tmp[8];
            #pragma unroll
            for (int cc = 0; cc < 8; ++cc)
                tmp[cc] = f32_to_bf16(((const float*)&breg[cc])[qq]);
            *(short8*)(BsD + (qq * 128 + rho * 16 + w16) * BPITCH + kw * 8) = *(short8*)tmp;
        }
    };
    auto stageA_glds = [&](int k0, uint16_t* AsD) {
        #pragma unroll
        for (int t = 0; t < 4; ++t) {
            // dest (row=t*16+(lane>>2), chunk=lane&3) linear; stored chunk c holds
            // global chunk c ^ ((row>>1)&3): pre-swizzle the SOURCE (rule #21).
            const uint16_t* src = abase + (size_t)(t * 16 + (lane >> 2)) * CS
                                        + k0 + (((lane & 3) ^ ((lane >> 3) & 3)) * 8);
            uint16_t* dst = AsD + (q * 128 + mw * 64) * 32 + t * 512;  // + lane*16B by HW
            __builtin_amdgcn_global_load_lds(
                (const __attribute__((address_space(1))) void*)src,
                (__attribute__((address_space(3))) void*)dst, 16, 0, 0);
        }
    };
    auto stageA_fp32 = [&](int k0, uint16_t* AsD) {
        const int qa = tid >> 7, rem = tid & 127;
        const int ka = rem & 7, ma = rem >> 3;
        const float* ap = Wg + ((size_t)(r * 4 + qa) * CT + m0 + ma) * CS + k0 + ka * 4;
        // stored chunk = (ka>>1) ^ ((row>>1)&3), row = ma + it*16 -> (ma>>1)&3
        const int kc = (((ka >> 1) ^ ((ma >> 1) & 3)) * 8) + (ka & 1) * 4;
        #pragma unroll
        for (int it = 0; it < 8; ++it) {
            float4 v = *(const float4*)(ap + (size_t)it * 16 * CS);
            uint16_t tmp[4] = {f32_to_bf16(v.x), f32_to_bf16(v.y),
                               f32_to_bf16(v.z), f32_to_bf16(v.w)};
            *(uint64_t*)(AsD + (qa * 128 + ma + it * 16) * 32 + kc) =
                *(const uint64_t*)tmp;
        }
    };

    f32x4 acc[4][8] = {};

    // ---- prologue: stage tile 0 into buf0, prefetch breg for tile 1
    {
        uint16_t* As0 = (uint16_t*)smem;
        uint16_t* Bs0 = (uint16_t*)(smem + 32768);
        loadB(0);
        if (USE_W2) stageA_glds(0, As0); else stageA_fp32(0, As0);
        writeB(Bs0);          // consumes breg(0); compiler-counted vmcnt
        loadB(BK);            // breg := tile 1
        __syncthreads();      // one conservative full drain (prologue only)
    }

    for (int k = 0; k < 16; ++k) {
        const uint16_t* Asq = (const uint16_t*)(smem + (k & 1) * BUFB)
                              + (q * 128 + mw * 64) * 32;
        const uint16_t* Bsq = (const uint16_t*)(smem + (k & 1) * BUFB + 32768)
                              + q * 128 * BPITCH;
        short8 afr[4], bfr[8];
        #pragma unroll
        for (int i = 0; i < 4; ++i)
            afr[i] = *(const short8*)(Asq + (i * 16 + lr) * 32
                                      + ((qd ^ ((lr >> 1) & 3)) * 8));
        #pragma unroll
        for (int j = 0; j < 8; ++j)
            bfr[j] = *(const short8*)(Bsq + (j * 16 + lr) * BPITCH + qd * 8);

        if (k < 15) {
            uint16_t* AsN = (uint16_t*)(smem + ((k + 1) & 1) * BUFB);
            uint16_t* BsN = (uint16_t*)(smem + ((k + 1) & 1) * BUFB + 32768);
            if (USE_W2) stageA_glds((k + 1) * BK, AsN); else stageA_fp32((k + 1) * BK, AsN);
            // pin VMEM issue order: glds (oldest) before loadB -> vmcnt(8) retires glds
            __builtin_amdgcn_sched_barrier(0x38F);
            writeB(BsN);                        // tile k+1 from breg (vmcnt(4) by compiler)
            if (k < 14) loadB((k + 2) * BK);    // breg := tile k+2
        }

        #pragma unroll
        for (int i = 0; i < 4; ++i)
            #pragma unroll
            for (int j = 0; j < 8; ++j)
                acc[i][j] = __builtin_amdgcn_mfma_f32_16x16x32_bf16(
                    afr[i], bfr[j], acc[i][j], 0, 0, 0);

        if (k < 15) {
            // counted wait: glds(k+1) (4, oldest) must land; loadB(k+2) (8) stays
            // in flight across the barrier (T4: never drain to 0 in main loop).
            if (k < 14) asm volatile("s_waitcnt vmcnt(8)" ::: "memory");
            else        asm volatile("s_waitcnt vmcnt(0)" ::: "memory");
            asm volatile("s_waitcnt lgkmcnt(0)" ::: "memory");
            __builtin_amdgcn_s_barrier();
        }
    }

    // ---- epilogue: LDS transpose -> full-line float4 stores
    // acc[i][j][g]: m = m0 + mw*64 + i*16 + qd*4+g, pixel n = j*16+lr
    //   -> rho = j, w16 = lr, w = lr*4 + q. chunk ic = mw*4 + i.
    const int m16s = tid >> 5;        // 0..15
    const int rs   = (tid >> 2) & 7;  // 0..7
    const int ws   = (tid & 3) * 16;
    const int rgs  = nb * NR + rs;
    const int obb  = rgs >> 4;
    const int oh4  = rgs & 15;
    #pragma unroll
    for (int ic = 0; ic < 8; ++ic) {
        __syncthreads();                       // prior reads of smem done
        if (mw == (ic >> 2)) {
            const int i = ic & 3;
            #pragma unroll
            for (int j = 0; j < 8; ++j)
                #pragma unroll
                for (int g = 0; g < 4; ++g)
                    T[((qd * 4 + g) * 8 + j) * 68 + lr * 4 + q] = acc[i][j][g];
        }
        __syncthreads();
        float* op = out + ((size_t)obb * CT + m0 + ic * 16 + m16s) * HW
                        + (oh4 * 4 + r) * 64 + ws;
        const float* tp = T + (m16s * 8 + rs) * 68 + ws;
        #pragma unroll
        for (int c = 0; c < 4; ++c)
            ((float4*)op)[c] = ((const float4*)tp)[c];
    }
}

extern "C" void kernel_launch(void* const* d_in, const int* in_sizes, int n_in,
                              void* d_out, int out_size, void* d_ws, size_t ws_size,
                              hipStream_t stream) {
    const float* x  = (const float*)d_in[0];
    const float* Wg = (const float*)d_in[1];
    float* out = (float*)d_out;
    dim3 grid(32, 4, 4);   // nb fastest: mb siblings (id stride 32) share an XCD
    if (ws_size >= (size_t)16 * 512 * 512 * 2) {
        uint16_t* W2 = (uint16_t*)d_ws;
        w2_cvt<<<2048, 256, 0, stream>>>(Wg, W2);
        gwl_main<true><<<grid, 512, 0, stream>>>(x, Wg, W2, out);
    } else {
        gwl_main<false><<<grid, 512, 0, stream>>>(x, Wg, nullptr, out);
    }
}